// Round 18
// baseline (2645.646 us; speedup 1.0000x reference)
//
#include <hip/hip_runtime.h>
#include <cstdint>
#include <cstddef>

#define BATCH   8
#define NPTS    8192
#define NPOINT  2048
#define NSAMPLE 64
#define K0      67      // 3 + 64 input channels
#define C2      128

typedef float v2f __attribute__((ext_vector_type(2)));

// Exact-order squared distance, matching XLA/numpy: ((dx*dx + dy*dy) + dz*dz),
// separate mul/add (no FMA contraction), round-to-nearest f32.
__device__ __forceinline__ float d2e(float ax, float ay, float az,
                                     float bx, float by, float bz) {
#pragma clang fp contract(off)
  float dx = ax - bx;
  float dy = ay - by;
  float dz = az - bz;
  float t0 = dx * dx;
  float t1 = dy * dy;
  float t2 = dz * dz;
  return (t0 + t1) + t2;
}

// ---- single fused wave64 reduction: u64 key min via DPP (same 6-step pattern
// validated bit-exact in R6-R17), result broadcast via readlane. Key packs
// (value desc, index asc): key = (~bits(v) << 13) | idx13.
__device__ __forceinline__ unsigned long long dpp_min_key(unsigned long long k) {
#define KSTEP(CTRL, RM, BM)                                                    \
  {                                                                            \
    int lo = (int)k, hi = (int)(k >> 32);                                      \
    int lo2 = __builtin_amdgcn_update_dpp(lo, lo, CTRL, RM, BM, false);        \
    int hi2 = __builtin_amdgcn_update_dpp(hi, hi, CTRL, RM, BM, false);        \
    unsigned long long k2 =                                                    \
        ((unsigned long long)(unsigned)hi2 << 32) | (unsigned)lo2;             \
    k = (k2 < k) ? k2 : k;                                                     \
  }
  KSTEP(0xB1, 0xF, 0xF)
  KSTEP(0x4E, 0xF, 0xF)
  KSTEP(0x141, 0xF, 0xF)
  KSTEP(0x140, 0xF, 0xF)
  KSTEP(0x142, 0xA, 0xF)
  KSTEP(0x143, 0xC, 0xF)
#undef KSTEP
  int lo = __builtin_amdgcn_readlane((int)k, 63);
  int hi = __builtin_amdgcn_readlane((int)(k >> 32), 63);
  return ((unsigned long long)(unsigned)hi << 32) | (unsigned)lo;
}

// ---------------- FPS: brute-force packed update, fused u64 reduce -----------
// R16-validated structure (1878 us). Thread tid owns 16 contiguous points as
// 8 float2 pairs; d2e+fmin update uses v_pk_*_f32 (two IEEE f32 ops per
// instr, bit-identical rounding, same per-element op order -> dd bit-exact).
// Tie-break scan scalar strict-> ascending (= first index); per-thread
// (bv,bj) packed into u64 key, ONE DPP min chain replaces max+min chains.
// No in-loop global stores; winners logged to u16 LDS; batched writeback.
__global__ __launch_bounds__(512) void fps_kernel(const float* __restrict__ xyz,
                                                  float* __restrict__ out_xyz,
                                                  float* __restrict__ out_inds) {
  const int b = blockIdx.x;
  const int tid = threadIdx.x;
  const int lane = tid & 63, w = tid >> 6;

  __shared__ float2 sxy[NPTS];                  // original order
  __shared__ float  szl[NPTS];
  __shared__ unsigned short sslot[NPOINT];      // winner index per t
  __shared__ unsigned long long wred[2][8] __attribute__((aligned(16)));

  const float* xb = xyz + (size_t)b * NPTS * 3;

  // --- coalesced stage to LDS
  for (int k = 0; k < 16; k++) {
    int i = tid + k * 512;
    sxy[i] = make_float2(xb[i * 3 + 0], xb[i * 3 + 1]);
    szl[i] = xb[i * 3 + 2];
  }
  __syncthreads();

  const float2 q0xy = sxy[0];
  const float q0x = q0xy.x, q0y = q0xy.y, q0z = szl[0];

  // --- own 16 contiguous points as 8 packed pairs, init dd (packed, exact)
  const int base = tid * 16;
  v2f px2[8], py2[8], pz2[8], dd2[8];
  {
#pragma clang fp contract(off)
#pragma unroll
    for (int k = 0; k < 8; k++) {
      float2 a = sxy[base + 2 * k];
      float2 c = sxy[base + 2 * k + 1];
      px2[k] = (v2f){a.x, c.x};
      py2[k] = (v2f){a.y, c.y};
      pz2[k] = (v2f){szl[base + 2 * k], szl[base + 2 * k + 1]};
      v2f dx = px2[k] - q0x;
      v2f dy = py2[k] - q0y;
      v2f dz = pz2[k] - q0z;
      v2f t0 = dx * dx;
      v2f t1 = dy * dy;
      v2f t2 = dz * dz;
      dd2[k] = (t0 + t1) + t2;
    }
  }
  if (tid == 0) sslot[0] = 0;

  // --- initial scan (strict >, ascending = first index) + fused reduce
  {
    float bv = -1.f; int bj = base;
#pragma unroll
    for (int k = 0; k < 8; k++) {
      float d0 = dd2[k].x, d1 = dd2[k].y;
      bool c0 = d0 > bv; bv = c0 ? d0 : bv; bj = c0 ? base + 2 * k : bj;
      bool c1 = d1 > bv; bv = c1 ? d1 : bv; bj = c1 ? base + 2 * k + 1 : bj;
    }
    unsigned long long kk =
        ((unsigned long long)(~__float_as_uint(bv)) << 13) | (unsigned)bj;
    kk = dpp_min_key(kk);
    if (lane == 0) wred[0][w] = kk;
  }
  __syncthreads();

  for (int t = 1; t < NPOINT; ++t) {
    // --- global winner = min of 8 wave keys (vectorized broadcast reads)
    const ulonglong2* wv = (const ulonglong2*)wred[(t - 1) & 1];
    ulonglong2 p0 = wv[0], p1 = wv[1], p2 = wv[2], p3 = wv[3];
    unsigned long long g0 = (p0.y < p0.x) ? p0.y : p0.x;
    unsigned long long g1 = (p1.y < p1.x) ? p1.y : p1.x;
    unsigned long long g2 = (p2.y < p2.x) ? p2.y : p2.x;
    unsigned long long g3 = (p3.y < p3.x) ? p3.y : p3.x;
    g0 = (g1 < g0) ? g1 : g0; g2 = (g3 < g2) ? g3 : g2;
    g0 = (g2 < g0) ? g2 : g0;
    const int nxt = (int)(g0 & 0x1FFFu);
    const float2 qxy = sxy[nxt];
    const float qx = qxy.x, qy = qxy.y, qz = szl[nxt];
    if (tid == 0) sslot[t] = (unsigned short)nxt;

    // --- packed straight-line update + scalar tie-aware scan (no branches)
    float bv = -1.f; int bj = base;
    {
#pragma clang fp contract(off)
#pragma unroll
      for (int k = 0; k < 8; k++) {
        v2f dx = px2[k] - qx;
        v2f dy = py2[k] - qy;
        v2f dz = pz2[k] - qz;
        v2f t0 = dx * dx;
        v2f t1 = dy * dy;
        v2f t2 = dz * dz;
        v2f d = (t0 + t1) + t2;
        v2f nd;
        nd.x = fminf(dd2[k].x, d.x);
        nd.y = fminf(dd2[k].y, d.y);
        dd2[k] = nd;
        bool c0 = nd.x > bv; bv = c0 ? nd.x : bv; bj = c0 ? base + 2 * k : bj;
        bool c1 = nd.y > bv; bv = c1 ? nd.y : bv; bj = c1 ? base + 2 * k + 1 : bj;
      }
    }
    unsigned long long kk =
        ((unsigned long long)(~__float_as_uint(bv)) << 13) | (unsigned)bj;
    kk = dpp_min_key(kk);
    if (lane == 0) wred[t & 1][w] = kk;
    __syncthreads();
  }

  // --- parallel writeback: inds + xyz from recorded winner indices
  for (int t = tid; t < NPOINT; t += 512) {
    int o = (int)sslot[t];
    float2 xy = sxy[o];
    out_inds[b * NPOINT + t] = (float)o;
    out_xyz[((size_t)b * NPOINT + t) * 3 + 0] = xy.x;
    out_xyz[((size_t)b * NPOINT + t) * 3 + 1] = xy.y;
    out_xyz[((size_t)b * NPOINT + t) * 3 + 2] = szl[o];
  }
}

// ---------------- prep: fold BN into per-channel consts ----------------------
// wsp floats: [0..255] A4[o]={sc0*W0x,sc0*W0y,sc0*W0z,sh0}; [256..319] sc1;
// [320..383] sh1; [384..511] sc2; [512..639] sh2; [640..703] sc0
__global__ __launch_bounds__(128) void prep_kernel(
    const float* __restrict__ W0, const float* __restrict__ g0,
    const float* __restrict__ b0, const float* __restrict__ m0,
    const float* __restrict__ v0, const float* __restrict__ g1,
    const float* __restrict__ b1, const float* __restrict__ m1,
    const float* __restrict__ v1, const float* __restrict__ g2,
    const float* __restrict__ b2, const float* __restrict__ m2,
    const float* __restrict__ v2, float* __restrict__ wsp) {
  const int tid = threadIdx.x;
  if (tid < 64) {
    float s0 = g0[tid] / sqrtf(v0[tid] + 1e-5f);
    wsp[4 * tid + 0] = s0 * W0[tid * K0 + 0];
    wsp[4 * tid + 1] = s0 * W0[tid * K0 + 1];
    wsp[4 * tid + 2] = s0 * W0[tid * K0 + 2];
    wsp[4 * tid + 3] = b0[tid] - m0[tid] * s0;
    wsp[640 + tid] = s0;
    float s1 = g1[tid] / sqrtf(v1[tid] + 1e-5f);
    wsp[256 + tid] = s1; wsp[320 + tid] = b1[tid] - m1[tid] * s1;
  }
  float s2 = g2[tid] / sqrtf(v2[tid] + 1e-5f);
  wsp[384 + tid] = s2; wsp[512 + tid] = b2[tid] - m2[tid] * s2;
}

// ---------------- zfeat: per-point L0 linear part ----------------------------
// szp[n][o] = sc0[o] * ( W0[o][0:3] . p_xyz + W0[o][3:67] . feat[:,n] )
__global__ __launch_bounds__(256) void zfeat_kernel(const float* __restrict__ xyz,
                                                    const float* __restrict__ feat,
                                                    const float* __restrict__ W0,
                                                    const float* __restrict__ wsp,
                                                    float* __restrict__ szp) {
  __shared__ float ftile[64][64];   // [c][u] - reads are wave-uniform
  __shared__ float sxyz[192];
  const int bt = blockIdx.x;        // b*128 + nt
  const int b = bt >> 7, nt = bt & 127;
  const int tid = threadIdx.x;
  const int lane = tid & 63, w = tid >> 6;

  const float* fb = feat + (size_t)b * 64 * NPTS + (size_t)nt * 64;
#pragma unroll
  for (int r = w; r < 64; r += 4)
    ftile[r][lane] = fb[(size_t)r * NPTS + lane];
  if (tid < 192)
    sxyz[tid] = xyz[((size_t)b * NPTS + (size_t)nt * 64) * 3 + tid];

  float w0x = W0[lane * K0 + 0], w0y = W0[lane * K0 + 1], w0z = W0[lane * K0 + 2];
  float wf[64];
#pragma unroll
  for (int i = 0; i < 64; i++) wf[i] = W0[lane * K0 + 3 + i];
  const float s0 = wsp[640 + lane];
  __syncthreads();

  float* ob = szp + ((size_t)b * NPTS + (size_t)nt * 64) * 64;
  for (int u = w; u < 64; u += 4) {
    float acc = w0x * sxyz[u * 3 + 0] + w0y * sxyz[u * 3 + 1] + w0z * sxyz[u * 3 + 2];
#pragma unroll
    for (int i = 0; i < 64; i++) acc = fmaf(wf[i], ftile[i][u], acc);
    ob[(size_t)u * 64 + lane] = acc * s0;
  }
}

// ---------------- fused ball-query + MLP + max-pool --------------------------
// lane = channel. Per query: inline ball query into LDS (body validated in
// R12-R15 mega workers), then R9 MLP body (672us tail form).
#define QPW 4
__global__ __launch_bounds__(256, 2) void mlp_kernel(
    const float* __restrict__ xyz, const float* __restrict__ szp,
    const float* __restrict__ new_xyz, const float* __restrict__ W1,
    const float* __restrict__ W2, const float* __restrict__ wsp,
    float* __restrict__ out_feat) {
  __shared__ float ylds[4][64];
  __shared__ int   blds[4][64];
  const int tid = threadIdx.x;
  const int lane = tid & 63, wid = tid >> 6;

  float4 w1v[16], w2av[16], w2bv[16];
  const float4* W1r = (const float4*)(W1 + lane * 64);
  const float4* W2ar = (const float4*)(W2 + lane * 64);
  const float4* W2br = (const float4*)(W2 + (lane + 64) * 64);
#pragma unroll
  for (int i = 0; i < 16; i++) { w1v[i] = W1r[i]; w2av[i] = W2ar[i]; w2bv[i] = W2br[i]; }
  const float4 A = ((const float4*)wsp)[lane];
  const float sc1l = wsp[256 + lane], sh1l = wsp[320 + lane];
  const float sc2al = wsp[384 + lane], sh2al = wsp[512 + lane];
  const float sc2bl = wsp[448 + lane], sh2bl = wsp[576 + lane];
  const float RR = (float)(0.4 * 0.4);

  int* bl = blds[wid];
  const float4* yv = (const float4*)ylds[wid];

  for (int qi = 0; qi < QPW; qi++) {
    const int q = blockIdx.x * (4 * QPW) + qi * 4 + wid;
    const int b = q >> 11, p = q & 2047;
    const float* xb = xyz + (size_t)b * NPTS * 3;
    const float* szb = szp + (size_t)b * NPTS * 64;

    const float cx = new_xyz[(size_t)q * 3 + 0];
    const float cy = new_xyz[(size_t)q * 3 + 1];
    const float cz = new_xyz[(size_t)q * 3 + 2];
    const float hc = A.w - (A.x * cx + A.y * cy + A.z * cz);

    // --- inline ball query (exact logic of validated ballq kernel)
    int cnt = 0, firsti = -1;
    for (int base2 = 0; base2 < NPTS; base2 += 64) {
      int i = base2 + lane;
      float xx = xb[i * 3 + 0], yy = xb[i * 3 + 1], zz = xb[i * 3 + 2];
      float dq = d2e(xx, yy, zz, cx, cy, cz);
      bool m = dq < RR;
      unsigned long long mask = __ballot(m);
      if (mask) {
        if (firsti < 0) firsti = base2 + (__ffsll((unsigned long long)mask) - 1);
        int pos = cnt + (int)__popcll(mask & ((1ull << lane) - 1ull));
        if (m && pos < NSAMPLE) bl[pos] = i;
        cnt += (int)__popcll(mask);
        if (cnt >= NSAMPLE) break;
      }
    }
    for (int s = cnt + lane; s < NSAMPLE; s += 64) bl[s] = firsti;
    __builtin_amdgcn_s_waitcnt(0);   // vm+lgkm: bl visible to own wave

    // --- MLP (R9 body)
    float vA = 0.f, vB = 0.f;
    int idx0 = bl[0];
    float fcur = szb[(size_t)idx0 * 64 + lane];

    for (int s = 0; s < NSAMPLE; s++) {
      int sn = (s < NSAMPLE - 1) ? s + 1 : s;
      int idxn = bl[sn];
      float fnext = szb[(size_t)idxn * 64 + lane];

      float y0 = fmaxf(fcur + hc, 0.f);
      ylds[wid][lane] = y0;
      float a0 = 0.f, a1 = 0.f, a2 = 0.f, a3 = 0.f;
#pragma unroll
      for (int i = 0; i < 16; i++) {
        float4 y = yv[i];
        a0 = fmaf(w1v[i].x, y.x, a0);
        a1 = fmaf(w1v[i].y, y.y, a1);
        a2 = fmaf(w1v[i].z, y.z, a2);
        a3 = fmaf(w1v[i].w, y.w, a3);
      }
      float y1 = fmaxf(fmaf((a0 + a1) + (a2 + a3), sc1l, sh1l), 0.f);
      ylds[wid][lane] = y1;
      float c0 = 0.f, c1 = 0.f, c2 = 0.f, c3 = 0.f;
      float e0 = 0.f, e1 = 0.f, e2 = 0.f, e3 = 0.f;
#pragma unroll
      for (int i = 0; i < 16; i++) {
        float4 y = yv[i];
        c0 = fmaf(w2av[i].x, y.x, c0);
        c1 = fmaf(w2av[i].y, y.y, c1);
        c2 = fmaf(w2av[i].z, y.z, c2);
        c3 = fmaf(w2av[i].w, y.w, c3);
        e0 = fmaf(w2bv[i].x, y.x, e0);
        e1 = fmaf(w2bv[i].y, y.y, e1);
        e2 = fmaf(w2bv[i].z, y.z, e2);
        e3 = fmaf(w2bv[i].w, y.w, e3);
      }
      float y2a = fmaxf(fmaf((c0 + c1) + (c2 + c3), sc2al, sh2al), 0.f);
      float y2b = fmaxf(fmaf((e0 + e1) + (e2 + e3), sc2bl, sh2bl), 0.f);
      vA = fmaxf(vA, y2a);
      vB = fmaxf(vB, y2b);
      fcur = fnext;
    }
    out_feat[((size_t)b * C2 + lane) * NPOINT + p] = vA;
    out_feat[((size_t)b * C2 + lane + 64) * NPOINT + p] = vB;
  }
}

extern "C" void kernel_launch(void* const* d_in, const int* in_sizes, int n_in,
                              void* d_out, int out_size, void* d_ws, size_t ws_size,
                              hipStream_t stream) {
  const float* xyz  = (const float*)d_in[0];
  const float* feat = (const float*)d_in[1];
  const float* W0 = (const float*)d_in[2];
  const float* g0 = (const float*)d_in[3];
  const float* b0 = (const float*)d_in[4];
  const float* m0 = (const float*)d_in[5];
  const float* v0 = (const float*)d_in[6];
  const float* W1 = (const float*)d_in[7];
  const float* g1 = (const float*)d_in[8];
  const float* b1 = (const float*)d_in[9];
  const float* m1 = (const float*)d_in[10];
  const float* v1 = (const float*)d_in[11];
  const float* W2 = (const float*)d_in[12];
  const float* g2 = (const float*)d_in[13];
  const float* b2 = (const float*)d_in[14];
  const float* m2 = (const float*)d_in[15];
  const float* v2 = (const float*)d_in[16];

  float* out = (float*)d_out;
  float* out_xyz  = out;                         // (8,2048,3)   = 49152
  float* out_feat = out + 49152;                 // (8,128,2048) = 2097152
  float* out_inds = out + 49152 + 2097152;       // (8,2048)     = 16384

  float* szp  = (float*)((char*)d_ws + 4194304);                 // 16.8 MiB
  float* wsp  = (float*)((char*)d_ws + 20971520);                // ~3 KiB

  hipLaunchKernelGGL(prep_kernel, dim3(1), dim3(128), 0, stream,
                     W0, g0, b0, m0, v0, g1, b1, m1, v1, g2, b2, m2, v2, wsp);
  hipLaunchKernelGGL(zfeat_kernel, dim3(BATCH * (NPTS / 64)), dim3(256), 0, stream,
                     xyz, feat, W0, wsp, szp);
  hipLaunchKernelGGL(fps_kernel, dim3(BATCH), dim3(512), 0, stream,
                     xyz, out_xyz, out_inds);
  hipLaunchKernelGGL(mlp_kernel, dim3((BATCH * NPOINT) / (4 * QPW)), dim3(256), 0, stream,
                     xyz, szp, out_xyz, W1, W2, wsp, out_feat);
}

// Round 19
// 2519.822 us; speedup vs baseline: 1.0499x; 1.0499x over previous
//
#include <hip/hip_runtime.h>
#include <cstdint>
#include <cstddef>

#define BATCH   8
#define NPTS    8192
#define NPOINT  2048
#define NSAMPLE 64
#define K0      67      // 3 + 64 input channels
#define C2      128

typedef float v2f __attribute__((ext_vector_type(2)));

// Exact-order squared distance, matching XLA/numpy: ((dx*dx + dy*dy) + dz*dz),
// separate mul/add (no FMA contraction), round-to-nearest f32.
__device__ __forceinline__ float d2e(float ax, float ay, float az,
                                     float bx, float by, float bz) {
#pragma clang fp contract(off)
  float dx = ax - bx;
  float dy = ay - by;
  float dz = az - bz;
  float t0 = dx * dx;
  float t1 = dy * dy;
  float t2 = dz * dz;
  return (t0 + t1) + t2;
}

// ---- single fused wave64 reduction: u64 key min via DPP (6-step pattern
// validated bit-exact R6-R18), result broadcast via readlane. Key packs
// (value desc, index asc): key = (~bits(v) << 13) | idx13.
__device__ __forceinline__ unsigned long long dpp_min_key(unsigned long long k) {
#define KSTEP(CTRL, RM, BM)                                                    \
  {                                                                            \
    int lo = (int)k, hi = (int)(k >> 32);                                      \
    int lo2 = __builtin_amdgcn_update_dpp(lo, lo, CTRL, RM, BM, false);        \
    int hi2 = __builtin_amdgcn_update_dpp(hi, hi, CTRL, RM, BM, false);        \
    unsigned long long k2 =                                                    \
        ((unsigned long long)(unsigned)hi2 << 32) | (unsigned)lo2;             \
    k = (k2 < k) ? k2 : k;                                                     \
  }
  KSTEP(0xB1, 0xF, 0xF)
  KSTEP(0x4E, 0xF, 0xF)
  KSTEP(0x141, 0xF, 0xF)
  KSTEP(0x140, 0xF, 0xF)
  KSTEP(0x142, 0xA, 0xF)
  KSTEP(0x143, 0xC, 0xF)
#undef KSTEP
  int lo = __builtin_amdgcn_readlane((int)k, 63);
  int hi = __builtin_amdgcn_readlane((int)(k >> 32), 63);
  return ((unsigned long long)(unsigned)hi << 32) | (unsigned)lo;
}

// ---------------- FPS: brute-force packed update, fused u64 reduce -----------
// R18-validated, 1845 us. Thread tid owns 16 contiguous points as 8 float2
// pairs; d2e+fmin update uses v_pk_*_f32 (two IEEE f32 ops per instr,
// bit-identical rounding, same per-element op order -> dd bit-exact).
// Tie-break scan scalar strict-> ascending (= first index); per-thread
// (bv,bj) packed into u64 key, ONE DPP min chain. No in-loop global stores;
// winners logged to u16 LDS; batched writeback.
__global__ __launch_bounds__(512) void fps_kernel(const float* __restrict__ xyz,
                                                  float* __restrict__ out_xyz,
                                                  float* __restrict__ out_inds) {
  const int b = blockIdx.x;
  const int tid = threadIdx.x;
  const int lane = tid & 63, w = tid >> 6;

  __shared__ float2 sxy[NPTS];                  // original order
  __shared__ float  szl[NPTS];
  __shared__ unsigned short sslot[NPOINT];      // winner index per t
  __shared__ unsigned long long wred[2][8] __attribute__((aligned(16)));

  const float* xb = xyz + (size_t)b * NPTS * 3;

  // --- coalesced stage to LDS
  for (int k = 0; k < 16; k++) {
    int i = tid + k * 512;
    sxy[i] = make_float2(xb[i * 3 + 0], xb[i * 3 + 1]);
    szl[i] = xb[i * 3 + 2];
  }
  __syncthreads();

  const float2 q0xy = sxy[0];
  const float q0x = q0xy.x, q0y = q0xy.y, q0z = szl[0];

  // --- own 16 contiguous points as 8 packed pairs, init dd (packed, exact)
  const int base = tid * 16;
  v2f px2[8], py2[8], pz2[8], dd2[8];
  {
#pragma clang fp contract(off)
#pragma unroll
    for (int k = 0; k < 8; k++) {
      float2 a = sxy[base + 2 * k];
      float2 c = sxy[base + 2 * k + 1];
      px2[k] = (v2f){a.x, c.x};
      py2[k] = (v2f){a.y, c.y};
      pz2[k] = (v2f){szl[base + 2 * k], szl[base + 2 * k + 1]};
      v2f dx = px2[k] - q0x;
      v2f dy = py2[k] - q0y;
      v2f dz = pz2[k] - q0z;
      v2f t0 = dx * dx;
      v2f t1 = dy * dy;
      v2f t2 = dz * dz;
      dd2[k] = (t0 + t1) + t2;
    }
  }
  if (tid == 0) sslot[0] = 0;

  // --- initial scan (strict >, ascending = first index) + fused reduce
  {
    float bv = -1.f; int bj = base;
#pragma unroll
    for (int k = 0; k < 8; k++) {
      float d0 = dd2[k].x, d1 = dd2[k].y;
      bool c0 = d0 > bv; bv = c0 ? d0 : bv; bj = c0 ? base + 2 * k : bj;
      bool c1 = d1 > bv; bv = c1 ? d1 : bv; bj = c1 ? base + 2 * k + 1 : bj;
    }
    unsigned long long kk =
        ((unsigned long long)(~__float_as_uint(bv)) << 13) | (unsigned)bj;
    kk = dpp_min_key(kk);
    if (lane == 0) wred[0][w] = kk;
  }
  __syncthreads();

  for (int t = 1; t < NPOINT; ++t) {
    // --- global winner = min of 8 wave keys (vectorized broadcast reads)
    const ulonglong2* wv = (const ulonglong2*)wred[(t - 1) & 1];
    ulonglong2 p0 = wv[0], p1 = wv[1], p2 = wv[2], p3 = wv[3];
    unsigned long long g0 = (p0.y < p0.x) ? p0.y : p0.x;
    unsigned long long g1 = (p1.y < p1.x) ? p1.y : p1.x;
    unsigned long long g2 = (p2.y < p2.x) ? p2.y : p2.x;
    unsigned long long g3 = (p3.y < p3.x) ? p3.y : p3.x;
    g0 = (g1 < g0) ? g1 : g0; g2 = (g3 < g2) ? g3 : g2;
    g0 = (g2 < g0) ? g2 : g0;
    const int nxt = (int)(g0 & 0x1FFFu);
    const float2 qxy = sxy[nxt];
    const float qx = qxy.x, qy = qxy.y, qz = szl[nxt];
    if (tid == 0) sslot[t] = (unsigned short)nxt;

    // --- packed straight-line update + scalar tie-aware scan (no branches)
    float bv = -1.f; int bj = base;
    {
#pragma clang fp contract(off)
#pragma unroll
      for (int k = 0; k < 8; k++) {
        v2f dx = px2[k] - qx;
        v2f dy = py2[k] - qy;
        v2f dz = pz2[k] - qz;
        v2f t0 = dx * dx;
        v2f t1 = dy * dy;
        v2f t2 = dz * dz;
        v2f d = (t0 + t1) + t2;
        v2f nd;
        nd.x = fminf(dd2[k].x, d.x);
        nd.y = fminf(dd2[k].y, d.y);
        dd2[k] = nd;
        bool c0 = nd.x > bv; bv = c0 ? nd.x : bv; bj = c0 ? base + 2 * k : bj;
        bool c1 = nd.y > bv; bv = c1 ? nd.y : bv; bj = c1 ? base + 2 * k + 1 : bj;
      }
    }
    unsigned long long kk =
        ((unsigned long long)(~__float_as_uint(bv)) << 13) | (unsigned)bj;
    kk = dpp_min_key(kk);
    if (lane == 0) wred[t & 1][w] = kk;
    __syncthreads();
  }

  // --- parallel writeback: inds + xyz from recorded winner indices
  for (int t = tid; t < NPOINT; t += 512) {
    int o = (int)sslot[t];
    float2 xy = sxy[o];
    out_inds[b * NPOINT + t] = (float)o;
    out_xyz[((size_t)b * NPOINT + t) * 3 + 0] = xy.x;
    out_xyz[((size_t)b * NPOINT + t) * 3 + 1] = xy.y;
    out_xyz[((size_t)b * NPOINT + t) * 3 + 2] = szl[o];
  }
}

// ---------------- prep: fold BN into per-channel consts ----------------------
// wsp floats: [0..255] A4[o]={sc0*W0x,sc0*W0y,sc0*W0z,sh0}; [256..319] sc1;
// [320..383] sh1; [384..511] sc2; [512..639] sh2; [640..703] sc0
__global__ __launch_bounds__(128) void prep_kernel(
    const float* __restrict__ W0, const float* __restrict__ g0,
    const float* __restrict__ b0, const float* __restrict__ m0,
    const float* __restrict__ v0, const float* __restrict__ g1,
    const float* __restrict__ b1, const float* __restrict__ m1,
    const float* __restrict__ v1, const float* __restrict__ g2,
    const float* __restrict__ b2, const float* __restrict__ m2,
    const float* __restrict__ v2, float* __restrict__ wsp) {
  const int tid = threadIdx.x;
  if (tid < 64) {
    float s0 = g0[tid] / sqrtf(v0[tid] + 1e-5f);
    wsp[4 * tid + 0] = s0 * W0[tid * K0 + 0];
    wsp[4 * tid + 1] = s0 * W0[tid * K0 + 1];
    wsp[4 * tid + 2] = s0 * W0[tid * K0 + 2];
    wsp[4 * tid + 3] = b0[tid] - m0[tid] * s0;
    wsp[640 + tid] = s0;
    float s1 = g1[tid] / sqrtf(v1[tid] + 1e-5f);
    wsp[256 + tid] = s1; wsp[320 + tid] = b1[tid] - m1[tid] * s1;
  }
  float s2 = g2[tid] / sqrtf(v2[tid] + 1e-5f);
  wsp[384 + tid] = s2; wsp[512 + tid] = b2[tid] - m2[tid] * s2;
}

// ---------------- zfeat: per-point L0 linear part ----------------------------
// szp[n][o] = sc0[o] * ( W0[o][0:3] . p_xyz + W0[o][3:67] . feat[:,n] )
__global__ __launch_bounds__(256) void zfeat_kernel(const float* __restrict__ xyz,
                                                    const float* __restrict__ feat,
                                                    const float* __restrict__ W0,
                                                    const float* __restrict__ wsp,
                                                    float* __restrict__ szp) {
  __shared__ float ftile[64][64];   // [c][u] - reads are wave-uniform
  __shared__ float sxyz[192];
  const int bt = blockIdx.x;        // b*128 + nt
  const int b = bt >> 7, nt = bt & 127;
  const int tid = threadIdx.x;
  const int lane = tid & 63, w = tid >> 6;

  const float* fb = feat + (size_t)b * 64 * NPTS + (size_t)nt * 64;
#pragma unroll
  for (int r = w; r < 64; r += 4)
    ftile[r][lane] = fb[(size_t)r * NPTS + lane];
  if (tid < 192)
    sxyz[tid] = xyz[((size_t)b * NPTS + (size_t)nt * 64) * 3 + tid];

  float w0x = W0[lane * K0 + 0], w0y = W0[lane * K0 + 1], w0z = W0[lane * K0 + 2];
  float wf[64];
#pragma unroll
  for (int i = 0; i < 64; i++) wf[i] = W0[lane * K0 + 3 + i];
  const float s0 = wsp[640 + lane];
  __syncthreads();

  float* ob = szp + ((size_t)b * NPTS + (size_t)nt * 64) * 64;
  for (int u = w; u < 64; u += 4) {
    float acc = w0x * sxyz[u * 3 + 0] + w0y * sxyz[u * 3 + 1] + w0z * sxyz[u * 3 + 2];
#pragma unroll
    for (int i = 0; i < 64; i++) acc = fmaf(wf[i], ftile[i][u], acc);
    ob[(size_t)u * 64 + lane] = acc * s0;
  }
}

// ---------------- ball query: one wave per query point -----------------------
__global__ __launch_bounds__(256) void ballq_kernel(const float* __restrict__ xyz,
                                                    const float* __restrict__ new_xyz,
                                                    int* __restrict__ ball) {
  const int lane = threadIdx.x & 63;
  const int q = blockIdx.x * 4 + (threadIdx.x >> 6);
  const int b = q >> 11;
  const float RR = (float)(0.4 * 0.4);
  const float cx = new_xyz[(size_t)q * 3 + 0];
  const float cy = new_xyz[(size_t)q * 3 + 1];
  const float cz = new_xyz[(size_t)q * 3 + 2];
  const float* xb = xyz + (size_t)b * NPTS * 3;
  int cnt = 0, firsti = -1;
  for (int base = 0; base < NPTS; base += 64) {
    int i = base + lane;
    float xx = xb[i * 3 + 0], yy = xb[i * 3 + 1], zz = xb[i * 3 + 2];
    float d2 = d2e(xx, yy, zz, cx, cy, cz);
    bool m = d2 < RR;
    unsigned long long mask = __ballot(m);
    if (mask) {
      if (firsti < 0) firsti = base + (__ffsll((unsigned long long)mask) - 1);
      int pos = cnt + (int)__popcll(mask & ((1ull << lane) - 1ull));
      if (m && pos < NSAMPLE) ball[(size_t)q * NSAMPLE + pos] = i;
      cnt += (int)__popcll(mask);
      if (cnt >= NSAMPLE) break;
    }
  }
  for (int s = cnt + lane; s < NSAMPLE; s += 64)
    ball[(size_t)q * NSAMPLE + s] = firsti;
}

// ---------------- MLP L1/L2 + max-pool: lane = channel (R9 body, 672us tail) -
#define QPW 4
__global__ __launch_bounds__(256, 2) void mlp_kernel(
    const float* __restrict__ szp, const int* __restrict__ ball,
    const float* __restrict__ new_xyz, const float* __restrict__ W1,
    const float* __restrict__ W2, const float* __restrict__ wsp,
    float* __restrict__ out_feat) {
  __shared__ float ylds[4][64];
  __shared__ int   blds[4][64];
  const int tid = threadIdx.x;
  const int lane = tid & 63, wid = tid >> 6;

  float4 w1v[16], w2av[16], w2bv[16];
  const float4* W1r = (const float4*)(W1 + lane * 64);
  const float4* W2ar = (const float4*)(W2 + lane * 64);
  const float4* W2br = (const float4*)(W2 + (lane + 64) * 64);
#pragma unroll
  for (int i = 0; i < 16; i++) { w1v[i] = W1r[i]; w2av[i] = W2ar[i]; w2bv[i] = W2br[i]; }
  const float4 A = ((const float4*)wsp)[lane];
  const float sc1l = wsp[256 + lane], sh1l = wsp[320 + lane];
  const float sc2al = wsp[384 + lane], sh2al = wsp[512 + lane];
  const float sc2bl = wsp[448 + lane], sh2bl = wsp[576 + lane];

  for (int qi = 0; qi < QPW; qi++) {
    const int q = blockIdx.x * (4 * QPW) + qi * 4 + wid;
    const int b = q >> 11, p = q & 2047;

    const float cx = new_xyz[(size_t)q * 3 + 0];
    const float cy = new_xyz[(size_t)q * 3 + 1];
    const float cz = new_xyz[(size_t)q * 3 + 2];
    const float hc = A.w - (A.x * cx + A.y * cy + A.z * cz);

    blds[wid][lane] = ball[(size_t)q * NSAMPLE + lane];
    const float* szb = szp + (size_t)b * NPTS * 64;
    __builtin_amdgcn_s_waitcnt(0);   // vm+lgkm: blds visible to own wave

    float vA = 0.f, vB = 0.f;
    int idx0 = blds[wid][0];
    float fcur = szb[(size_t)idx0 * 64 + lane];
    const float4* yv = (const float4*)ylds[wid];

    for (int s = 0; s < NSAMPLE; s++) {
      int sn = (s < NSAMPLE - 1) ? s + 1 : s;
      int idxn = blds[wid][sn];
      float fnext = szb[(size_t)idxn * 64 + lane];

      float y0 = fmaxf(fcur + hc, 0.f);
      ylds[wid][lane] = y0;
      float a0 = 0.f, a1 = 0.f, a2 = 0.f, a3 = 0.f;
#pragma unroll
      for (int i = 0; i < 16; i++) {
        float4 y = yv[i];
        a0 = fmaf(w1v[i].x, y.x, a0);
        a1 = fmaf(w1v[i].y, y.y, a1);
        a2 = fmaf(w1v[i].z, y.z, a2);
        a3 = fmaf(w1v[i].w, y.w, a3);
      }
      float y1 = fmaxf(fmaf((a0 + a1) + (a2 + a3), sc1l, sh1l), 0.f);
      ylds[wid][lane] = y1;
      float c0 = 0.f, c1 = 0.f, c2 = 0.f, c3 = 0.f;
      float e0 = 0.f, e1 = 0.f, e2 = 0.f, e3 = 0.f;
#pragma unroll
      for (int i = 0; i < 16; i++) {
        float4 y = yv[i];
        c0 = fmaf(w2av[i].x, y.x, c0);
        c1 = fmaf(w2av[i].y, y.y, c1);
        c2 = fmaf(w2av[i].z, y.z, c2);
        c3 = fmaf(w2av[i].w, y.w, c3);
        e0 = fmaf(w2bv[i].x, y.x, e0);
        e1 = fmaf(w2bv[i].y, y.y, e1);
        e2 = fmaf(w2bv[i].z, y.z, e2);
        e3 = fmaf(w2bv[i].w, y.w, e3);
      }
      float y2a = fmaxf(fmaf((c0 + c1) + (c2 + c3), sc2al, sh2al), 0.f);
      float y2b = fmaxf(fmaf((e0 + e1) + (e2 + e3), sc2bl, sh2bl), 0.f);
      vA = fmaxf(vA, y2a);
      vB = fmaxf(vB, y2b);
      fcur = fnext;
    }
    out_feat[((size_t)b * C2 + lane) * NPOINT + p] = vA;
    out_feat[((size_t)b * C2 + lane + 64) * NPOINT + p] = vB;
  }
}

extern "C" void kernel_launch(void* const* d_in, const int* in_sizes, int n_in,
                              void* d_out, int out_size, void* d_ws, size_t ws_size,
                              hipStream_t stream) {
  const float* xyz  = (const float*)d_in[0];
  const float* feat = (const float*)d_in[1];
  const float* W0 = (const float*)d_in[2];
  const float* g0 = (const float*)d_in[3];
  const float* b0 = (const float*)d_in[4];
  const float* m0 = (const float*)d_in[5];
  const float* v0 = (const float*)d_in[6];
  const float* W1 = (const float*)d_in[7];
  const float* g1 = (const float*)d_in[8];
  const float* b1 = (const float*)d_in[9];
  const float* m1 = (const float*)d_in[10];
  const float* v1 = (const float*)d_in[11];
  const float* W2 = (const float*)d_in[12];
  const float* g2 = (const float*)d_in[13];
  const float* b2 = (const float*)d_in[14];
  const float* m2 = (const float*)d_in[15];
  const float* v2 = (const float*)d_in[16];

  float* out = (float*)d_out;
  float* out_xyz  = out;                         // (8,2048,3)   = 49152
  float* out_feat = out + 49152;                 // (8,128,2048) = 2097152
  float* out_inds = out + 49152 + 2097152;       // (8,2048)     = 16384

  int*   ball = (int*)d_ws;                                      // 4 MiB
  float* szp  = (float*)((char*)d_ws + 4194304);                 // 16.8 MiB
  float* wsp  = (float*)((char*)d_ws + 20971520);                // ~3 KiB

  hipLaunchKernelGGL(prep_kernel, dim3(1), dim3(128), 0, stream,
                     W0, g0, b0, m0, v0, g1, b1, m1, v1, g2, b2, m2, v2, wsp);
  hipLaunchKernelGGL(zfeat_kernel, dim3(BATCH * (NPTS / 64)), dim3(256), 0, stream,
                     xyz, feat, W0, wsp, szp);
  hipLaunchKernelGGL(fps_kernel, dim3(BATCH), dim3(512), 0, stream,
                     xyz, out_xyz, out_inds);
  hipLaunchKernelGGL(ballq_kernel, dim3((BATCH * NPOINT) / 4), dim3(256), 0, stream,
                     xyz, out_xyz, ball);
  hipLaunchKernelGGL(mlp_kernel, dim3((BATCH * NPOINT) / (4 * QPW)), dim3(256), 0, stream,
                     szp, ball, out_xyz, W1, W2, wsp, out_feat);
}